// Round 15
// baseline (779.203 us; speedup 1.0000x reference)
//
#include <hip/hip_runtime.h>

// ---- problem dims ----
#define IN_DIM 8193
#define OUT_DIM 4097
#define NB 1024
#define KP1 8256   // 129 * 64  (K for t = W4·x)
#define M2 4096    // t/out rows 0..4095; row 4096 handled separately
#define KP2 4160   // 65 * 64   (K for out = A·t)

typedef __attribute__((ext_vector_type(8))) short short8;
typedef __attribute__((ext_vector_type(4))) float f32x4;

__device__ __forceinline__ unsigned short f2bf(float f) {
  unsigned int u = __float_as_uint(f);
  u = (u + 0x7fffu + ((u >> 16) & 1u)) >> 16;  // RNE
  return (unsigned short)u;
}
__device__ __forceinline__ float bf2f(unsigned short u) {
  return __uint_as_float(((unsigned int)u) << 16);
}

// ---- pad + f32->bf16 convert (row-major -> row-major padded) ----
__global__ __launch_bounds__(256) void cvt_pad_kernel(
    const float* __restrict__ src, unsigned short* __restrict__ dst,
    int sR, int sC, int dR, int dC) {
  int gid = blockIdx.x * 256 + threadIdx.x;
  int i4 = gid * 4;
  if (i4 >= dR * dC) return;
  int r = i4 / dC;
  int c = i4 - r * dC;
  unsigned short o[4];
#pragma unroll
  for (int j = 0; j < 4; ++j) {
    int cc = c + j;
    float v = (r < sR && cc < sC) ? src[(size_t)r * sC + cc] : 0.f;
    o[j] = f2bf(v);
  }
  unsigned int lo = (unsigned)o[0] | ((unsigned)o[1] << 16);
  unsigned int hi = (unsigned)o[2] | ((unsigned)o[3] << 16);
  *reinterpret_cast<uint2*>(dst + i4) = make_uint2(lo, hi);
}

// ---- transpose+convert x -> xT bf16, FUSED hom row: zh[n] += Ainv[8192,:]·x[:,n] ----
__global__ __launch_bounds__(256) void transpose_cvt_zh_kernel(
    const float* __restrict__ src, unsigned short* __restrict__ dst,
    const float* __restrict__ arow, float* __restrict__ zh,
    int K, int N, int Kp) {
  __shared__ float tl[32][33];
  const int ntk = Kp >> 5;
  int bx = blockIdx.x % ntk;
  int by = blockIdx.x / ntk;
  int k0 = bx * 32, n0 = by * 32;
  int tx = threadIdx.x & 31, ty = threadIdx.x >> 5;
#pragma unroll
  for (int i = 0; i < 4; ++i) {
    int k = k0 + ty + i * 8;
    tl[ty + i * 8][tx] = (k < K) ? src[(size_t)k * N + n0 + tx] : 0.f;
  }
  const float av = (k0 + tx < K) ? arow[k0 + tx] : 0.f;
  __syncthreads();
#pragma unroll
  for (int i = 0; i < 4; ++i) {
    int n = n0 + ty + i * 8;
    float v = tl[tx][ty + i * 8];
    dst[(size_t)n * Kp + k0 + tx] = f2bf(v);
    float c = av * v;
#pragma unroll
    for (int m = 1; m <= 16; m <<= 1) c += __shfl_xor(c, m);
    if (tx == 0) atomicAdd(&zh[n], c);
  }
}

// ---- float4 zero ----
__global__ __launch_bounds__(256) void zero_kernel(float4* __restrict__ p, int n) {
  int i = blockIdx.x * 256 + threadIdx.x;
  if (i < n) p[i] = make_float4(0.f, 0.f, 0.f, 0.f);
}

// ---- W4 = T·Ainv build, ILP version: thread owns 4 consecutive columns ----
// W4[r=(co,uo,vo), c] = sum_{taps} w[co,ci,kh,kw]·Ainv[(ci,2uo+kh,2vo+kw), c]
//                       + bias[co]·Ainv[8192, c]   (f32 math, ONE bf16 round)
// acc[16][4] (~64 VGPR) forces a deep outstanding-load window (R14's 1-col
// version had VGPR=28 -> zero ILP -> latency-bound at 318us). Ainv rows are
// only 4B-aligned (stride 8193) so loads stay scalar dwords; 4 independent
// per tap. Grid 2048 = uv*8+oct; default XCD=bid%8=oct -> each XCD owns one
// column-stripe of ALL rows (stripe re-reads hit its own L2).
__global__ __launch_bounds__(256) void w4_build_kernel(
    const float* __restrict__ Ainv, const float* __restrict__ w,
    const float* __restrict__ bias, unsigned short* __restrict__ W4) {
  __shared__ float wl[1152];
  __shared__ float bl[16];
  const int b = blockIdx.x;        // 2048 = uv*8 + oct
  const int oct = b & 7;
  const int uv = b >> 3;
  const int uo = uv >> 4, vo = uv & 15;
  const int tid = threadIdx.x;
#pragma unroll
  for (int it = 0; it < 5; ++it) {
    const int i = it * 256 + tid;
    if (i < 1152) wl[i] = w[i];
  }
  if (tid < 16) bl[tid] = bias[tid];
  __syncthreads();
  const int r0 = uo * 16 + vo;
  const int s0 = oct * 258;  // 8*258 = 2064 = KP1/4 slots
  for (int s = s0 + tid; s < s0 + 258; s += 256) {
    const int c = s * 4;
    unsigned short o[16][4];
    if (s <= 2047) {
      // fast path: 4 real cols
      float acc[16][4];
      const float* hp = Ainv + (size_t)8192 * IN_DIM + c;
      {
        const float h0 = hp[0], h1 = hp[1], h2 = hp[2], h3 = hp[3];
#pragma unroll
        for (int co = 0; co < 16; ++co) {
          const float bb = bl[co];
          acc[co][0] = bb * h0; acc[co][1] = bb * h1;
          acc[co][2] = bb * h2; acc[co][3] = bb * h3;
        }
      }
#pragma unroll
      for (int kh = 0; kh < 3; ++kh) {
        const int u = 2 * uo + kh;
        if (u >= 32) continue;
#pragma unroll
        for (int kw = 0; kw < 3; ++kw) {
          const int v = 2 * vo + kw;
          if (v >= 32) continue;
#pragma unroll
          for (int ci = 0; ci < 8; ++ci) {
            const float* ap =
                Ainv + (size_t)(ci * 1024 + u * 32 + v) * IN_DIM + c;
            const float t0 = ap[0], t1 = ap[1], t2 = ap[2], t3 = ap[3];
            const float* wp = wl + ci * 9 + kh * 3 + kw;
#pragma unroll
            for (int co = 0; co < 16; ++co) {
              const float wv = wp[co * 72];
              acc[co][0] += wv * t0; acc[co][1] += wv * t1;
              acc[co][2] += wv * t2; acc[co][3] += wv * t3;
            }
          }
        }
      }
#pragma unroll
      for (int co = 0; co < 16; ++co)
#pragma unroll
        for (int j = 0; j < 4; ++j) o[co][j] = f2bf(acc[co][j]);
    } else if (c < IN_DIM) {
      // boundary slot (col 8192 real, 3 pad) — one thread per grid row
      float accs[16];
      const float hv = Ainv[(size_t)8192 * IN_DIM + c];
#pragma unroll
      for (int co = 0; co < 16; ++co) accs[co] = bl[co] * hv;
      for (int kh = 0; kh < 3; ++kh) {
        const int u = 2 * uo + kh;
        if (u >= 32) continue;
        for (int kw = 0; kw < 3; ++kw) {
          const int v = 2 * vo + kw;
          if (v >= 32) continue;
          for (int ci = 0; ci < 8; ++ci) {
            const float a =
                Ainv[(size_t)(ci * 1024 + u * 32 + v) * IN_DIM + c];
            const float* wp = wl + ci * 9 + kh * 3 + kw;
#pragma unroll
            for (int co = 0; co < 16; ++co) accs[co] += wp[co * 72] * a;
          }
        }
      }
#pragma unroll
      for (int co = 0; co < 16; ++co) {
        o[co][0] = f2bf(accs[co]);
        o[co][1] = o[co][2] = o[co][3] = 0;
      }
    } else {
#pragma unroll
      for (int co = 0; co < 16; ++co)
#pragma unroll
        for (int j = 0; j < 4; ++j) o[co][j] = 0;
    }
#pragma unroll
    for (int co = 0; co < 16; ++co) {
      const unsigned lo = (unsigned)o[co][0] | ((unsigned)o[co][1] << 16);
      const unsigned hi = (unsigned)o[co][2] | ((unsigned)o[co][3] << 16);
      *reinterpret_cast<uint2*>(W4 + (size_t)(co * 256 + r0) * KP1 + c) =
          make_uint2(lo, hi);
    }
  }
}

// ---- 8-barrier 4-phase pipelined GEMM (R13-validated), 256 blocks ----
template <int NKT, int NSPLIT, int BMBITS, int MROWS>
__global__ __launch_bounds__(512) void gemm_dp(
    const unsigned short* __restrict__ Ab,
    const unsigned short* __restrict__ Bt,
    float* __restrict__ C, int Kp) {
  extern __shared__ unsigned short lds[];  // 8 * 8192 shorts = 128 KB
  const int tid = threadIdx.x;
  const int wid = tid >> 6;
  const int lane = tid & 63;
  const int b = blockIdx.x;
  const int x = b & 7, q = b >> 3;
  const int bm = (q & ((1 << BMBITS) - 1)) * 8 + x;
  const int bn = (q >> BMBITS) & 3;
  const int sp = q >> (BMBITS + 2);
  const int wm = (wid >> 2) << 7;  // 0 / 128
  const int wn = (wid & 3) << 6;   // 0 / 64 / 128 / 192

  const int qk = NKT / NSPLIT, rrk = NKT % NSPLIT;
  const int kt0 = sp * qk + (sp < rrk ? sp : rrk);
  const int T = qk + (sp < rrk ? 1 : 0);
  float* Cp = C + (size_t)sp * MROWS * NB;

  const int g0 = ((lane >> 4) ^ (lane & 7)) * 8;        // kk=0
  const int g1 = ((4 + (lane >> 4)) ^ (lane & 7)) * 8;  // kk=1
  const int alo = (lane & 15) * 64;
  const int bhalf = (wn >> 7) << 1;
  const int ahalf = (wid >> 2) << 1;
  const int bsub = ((wn & 64) << 6) + alo;

#define STAGEH(TT, ISA, H)                                                     \
  do {                                                                         \
    const int tt_ = (TT);                                                      \
    const int kc_ = kt0 + (tt_ < T - 1 ? tt_ : T - 1);                         \
    const int par_ = tt_ & 1;                                                  \
    const unsigned short* M_ = (ISA) ? Ab : Bt;                                \
    const int br_ = ((ISA) ? bm : bn) << 8;                                    \
    _Pragma("unroll")                                                          \
    for (int L_ = 0; L_ < 2; ++L_) {                                           \
      const int s_ = L_ * 512 + tid;                                           \
      const int row_ = s_ >> 3;                                                \
      const int gl_ = (s_ & 7) ^ (row_ & 7);                                   \
      const unsigned short* g_ = M_ + (size_t)(br_ + ((H) << 7) + row_) * Kp   \
                                    + (kc_ << 6) + gl_ * 8;                    \
      unsigned short* l_ = lds + (((ISA) ? 0 : 4) + ((H) << 1) + par_) * 8192  \
                               + (size_t)(L_ * 512 + wid * 64) * 8;            \
      __builtin_amdgcn_global_load_lds(                                        \
          (const __attribute__((address_space(1))) void*)g_,                   \
          (__attribute__((address_space(3))) void*)l_, 16, 0, 0);              \
    }                                                                          \
  } while (0)

#define MFMA16(BV0, BV1, NF0, NF1)                                             \
  do {                                                                         \
    __builtin_amdgcn_s_setprio(1);                                             \
    _Pragma("unroll")                                                          \
    for (int mf_ = 0; mf_ < 8; ++mf_) {                                        \
      asm volatile("v_mfma_f32_16x16x32_bf16 %0, %1, %2, %0"                   \
                   : "+v"(acc[mf_][NF0]) : "v"(af[mf_]), "v"(BV0));            \
      asm volatile("v_mfma_f32_16x16x32_bf16 %0, %1, %2, %0"                   \
                   : "+v"(acc[mf_][NF1]) : "v"(af[mf_]), "v"(BV1));            \
    }                                                                          \
    __builtin_amdgcn_s_setprio(0);                                             \
  } while (0)

#define PHASE_SYNC()                                                           \
  do {                                                                         \
    __builtin_amdgcn_s_barrier();                                              \
    asm volatile("s_waitcnt lgkmcnt(0)" ::: "memory");                         \
    __builtin_amdgcn_sched_barrier(0);                                         \
  } while (0)

  f32x4 acc[8][4];
#pragma unroll
  for (int i = 0; i < 8; ++i)
#pragma unroll
    for (int j = 0; j < 4; ++j) acc[i][j] = (f32x4)(0.0f);

  STAGEH(0, 1, 0); STAGEH(0, 1, 1);
  STAGEH(0, 0, 0); STAGEH(0, 0, 1);
  STAGEH(1, 1, 0); STAGEH(1, 1, 1);
  asm volatile("s_waitcnt vmcnt(4)" ::: "memory");
  __builtin_amdgcn_s_barrier();

  for (int t = 0; t < T; ++t) {
    const int par = t & 1;
    const unsigned short* Ab_ = lds + (ahalf + par) * 8192 + alo;
    const unsigned short* Bb_ = lds + (4 + bhalf + par) * 8192 + bsub;
    short8 af[8], b0, b1;
    // ---- Ph1 ----
    STAGEH(t + 1, 0, 0);
#pragma unroll
    for (int mf = 0; mf < 8; ++mf)
      af[mf] = *reinterpret_cast<const short8*>(Ab_ + mf * 1024 + g0);
    b0 = *reinterpret_cast<const short8*>(Bb_ + 0 * 1024 + g0);
    b1 = *reinterpret_cast<const short8*>(Bb_ + 1 * 1024 + g0);
    PHASE_SYNC();
    MFMA16(b0, b1, 0, 1);
    __builtin_amdgcn_s_barrier();
    // ---- Ph2 ----
    STAGEH(t + 1, 0, 1);
    b0 = *reinterpret_cast<const short8*>(Bb_ + 2 * 1024 + g0);
    b1 = *reinterpret_cast<const short8*>(Bb_ + 3 * 1024 + g0);
    PHASE_SYNC();
    MFMA16(b0, b1, 2, 3);
    __builtin_amdgcn_s_barrier();
    // ---- Ph3 ----
#pragma unroll
    for (int mf = 0; mf < 8; ++mf)
      af[mf] = *reinterpret_cast<const short8*>(Ab_ + mf * 1024 + g1);
    b0 = *reinterpret_cast<const short8*>(Bb_ + 2 * 1024 + g1);
    b1 = *reinterpret_cast<const short8*>(Bb_ + 3 * 1024 + g1);
    PHASE_SYNC();
    MFMA16(b0, b1, 2, 3);
    __builtin_amdgcn_s_barrier();
    // ---- Ph4 ----
    STAGEH(t + 2, 1, 0); STAGEH(t + 2, 1, 1);
    b0 = *reinterpret_cast<const short8*>(Bb_ + 0 * 1024 + g1);
    b1 = *reinterpret_cast<const short8*>(Bb_ + 1 * 1024 + g1);
    asm volatile("s_waitcnt vmcnt(4)" ::: "memory");
    PHASE_SYNC();
    MFMA16(b0, b1, 0, 1);
    __builtin_amdgcn_s_barrier();
  }
#undef STAGEH
#undef MFMA16
#undef PHASE_SYNC

#pragma unroll
  for (int mf = 0; mf < 8; ++mf) {
    const int rb = (bm << 8) + wm + mf * 16 + ((lane >> 4) << 2);
#pragma unroll
    for (int nf = 0; nf < 4; ++nf) {
      const int col = (bn << 8) + wn + nf * 16 + (lane & 15);
#pragma unroll
      for (int r = 0; r < 4; ++r)
        Cp[(size_t)(rb + r) * NB + col] = acc[mf][nf][r];
    }
  }
}

// ---- sum 4 t-partials + transpose + cvt -> tT rows 0..4095 ----
__global__ __launch_bounds__(256) void sum4t_kernel(
    const float* __restrict__ tp, unsigned short* __restrict__ tT) {
  __shared__ float tl[32][33];
  const int nr = M2 / 32;           // 128 r-tiles
  const int br = blockIdx.x % nr;
  const int bn = blockIdx.x / nr;   // 32 n-tiles
  const int r0 = br * 32, n0 = bn * 32;
  const int tx = threadIdx.x & 31, ty = threadIdx.x >> 5;
  const size_t S = (size_t)M2 * NB;
#pragma unroll
  for (int i = 0; i < 4; ++i) {
    const int r = r0 + ty + i * 8;
    const size_t g = (size_t)r * NB + n0 + tx;
    tl[ty + i * 8][tx] = (tp[g] + tp[g + S]) + (tp[g + 2 * S] + tp[g + 3 * S]);
  }
  __syncthreads();
#pragma unroll
  for (int i = 0; i < 4; ++i) {
    const int n = n0 + ty + i * 8;
    tT[(size_t)n * KP2 + r0 + tx] = f2bf(tl[tx][ty + i * 8]);
  }
}

// ---- tT rows 4096..4159: hom row + zero pad ----
__global__ __launch_bounds__(256) void homrow_kernel(
    const float* __restrict__ zh, unsigned short* __restrict__ tT) {
  const int n = blockIdx.x * 256 + threadIdx.x;
  unsigned short* p = tT + (size_t)n * KP2 + 4096;
  uint4 z4 = make_uint4(0u, 0u, 0u, 0u);
  uint4 h4 = z4;
  h4.x = (unsigned)f2bf(zh[n]);
  *reinterpret_cast<uint4*>(p) = h4;
#pragma unroll
  for (int i = 1; i < 8; ++i) *reinterpret_cast<uint4*>(p + i * 8) = z4;
}

// ---- final sum of 4 split-K partials -> d_out rows 0..4095 ----
__global__ __launch_bounds__(256) void sum4_kernel(
    const float* __restrict__ p, float* __restrict__ out, int n4) {
  const int i = blockIdx.x * 256 + threadIdx.x;
  if (i >= n4) return;
  const size_t stride4 = (size_t)M2 * NB / 4;
  const float4* p4 = (const float4*)p;
  float4 a = p4[i];
  float4 b = p4[i + stride4];
  float4 c = p4[i + 2 * stride4];
  float4 d = p4[i + 3 * stride4];
  float4 r;
  r.x = (a.x + b.x) + (c.x + d.x);
  r.y = (a.y + b.y) + (c.y + d.y);
  r.z = (a.z + b.z) + (c.z + d.z);
  r.w = (a.w + b.w) + (c.w + d.w);
  reinterpret_cast<float4*>(out)[i] = r;
}

// ---- out row 4096: wave-per-column dot over bf16 A2 row x tT ----
__global__ __launch_bounds__(256) void outrow_kernel(
    const unsigned short* __restrict__ A2row,
    const unsigned short* __restrict__ tT, float* __restrict__ out) {
  const int wid = threadIdx.x >> 6, lane = threadIdx.x & 63;
  const int n = blockIdx.x * 4 + wid;
  const unsigned short* trow = tT + (size_t)n * KP2;
  float acc = 0.f;
#pragma unroll
  for (int it = 0; it < 9; ++it) {
    const int i8 = it * 64 + lane;
    if (i8 < KP2 / 8) {
      short8 tv = *reinterpret_cast<const short8*>(trow + i8 * 8);
      short8 av = *reinterpret_cast<const short8*>(A2row + i8 * 8);
#pragma unroll
      for (int j = 0; j < 8; ++j)
        acc += bf2f((unsigned short)tv[j]) * bf2f((unsigned short)av[j]);
    }
  }
#pragma unroll
  for (int m = 1; m <= 32; m <<= 1) acc += __shfl_xor(acc, m);
  if (lane == 0) out[(size_t)4096 * NB + n] = acc;
}

extern "C" void kernel_launch(void* const* d_in, const int* in_sizes, int n_in,
                              void* d_out, int out_size, void* d_ws, size_t ws_size,
                              hipStream_t stream) {
  const float* w    = (const float*)d_in[0];  // (16,8,3,3)
  const float* bias = (const float*)d_in[1];  // (16,)
  const float* A    = (const float*)d_in[2];  // (4097,4097)
  const float* Ainv = (const float*)d_in[3];  // (8193,8193)
  const float* x    = (const float*)d_in[4];  // (8193,1024)
  float* out = (float*)d_out;                 // (4097,1024)

  // Workspace (160.2 MB):
  //   [0]      W4 4096xKP1 bf16 = 67.6 MB (dead after GEMM_t; outp 67.1 aliases)
  //   [67.6]   xT_b 1024xKP1 bf16 = 16.9 MB
  //   [84.5]   tp 4x4096x1024 f32 = 67.1 MB (dead after sum4t; A2_b 34.1 aliases)
  //   [151.6]  tT_b 1024xKP2 bf16 = 8.5 MB
  //   [160.1]  zh 1024 f32
  char* ws = (char*)d_ws;
  const size_t o_xT = (size_t)M2 * KP1 * 2;
  const size_t o_tp = o_xT + (size_t)NB * KP1 * 2;
  const size_t o_tT = o_tp + (size_t)4 * M2 * NB * 4;
  const size_t o_zh = o_tT + (size_t)NB * KP2 * 2;
  unsigned short* W4   = (unsigned short*)ws;
  unsigned short* xT_b = (unsigned short*)(ws + o_xT);
  float*          tp   = (float*)(ws + o_tp);
  unsigned short* tT_b = (unsigned short*)(ws + o_tT);
  float*          zh   = (float*)(ws + o_zh);
  unsigned short* A2_b = (unsigned short*)(ws + o_tp);  // aliases tp
  float*          outp = (float*)ws;                    // aliases W4
  (void)ws_size; (void)in_sizes; (void)n_in; (void)out_size;

  hipFuncSetAttribute((const void*)gemm_dp<129, 4, 1, M2>,
                      hipFuncAttributeMaxDynamicSharedMemorySize, 131072);
  hipFuncSetAttribute((const void*)gemm_dp<65, 4, 1, M2>,
                      hipFuncAttributeMaxDynamicSharedMemorySize, 131072);

  // 1) zero zh
  zero_kernel<<<1, 256, 0, stream>>>((float4*)zh, 256);
  // 2) x -> x^T bf16 + fused zh = Ainv[8192,:] @ x
  transpose_cvt_zh_kernel<<<(KP1 / 32) * (NB / 32), 256, 0, stream>>>(
      x, xT_b, Ainv + (size_t)8192 * IN_DIM, zh, IN_DIM, NB, KP1);
  // 3) W4 = T·Ainv (bias folded), bf16 padded (4096 x KP1), ILP build
  w4_build_kernel<<<2048, 256, 0, stream>>>(Ainv, w, bias, W4);
  // 4) tp[0..3] = W4 @ x  (4-phase GEMM, split-K=4, exactly 256 blocks)
  gemm_dp<129, 4, 1, M2><<<256, 512, 131072, stream>>>(
      W4, xT_b, tp, KP1);
  // 5) t^T rows 0..4095 = sum partials + transpose + cvt
  sum4t_kernel<<<(M2 / 32) * (NB / 32), 256, 0, stream>>>(tp, tT_b);
  // 6) t^T rows 4096..4159 = hom + zero pad
  homrow_kernel<<<4, 256, 0, stream>>>(zh, tT_b);
  // 7) A rows 0..4096 -> padded bf16 (aliases dead tp)
  cvt_pad_kernel<<<(OUT_DIM * KP2 / 4 + 255) / 256, 256, 0, stream>>>(
      A, A2_b, OUT_DIM, OUT_DIM, OUT_DIM, KP2);
  // 8) outp[0..3] = A @ t  (4-phase GEMM, split-K=4; outp aliases dead W4)
  gemm_dp<65, 4, 1, M2><<<256, 512, 131072, stream>>>(
      A2_b, tT_b, outp, KP2);
  // 9) out rows 0..4095 = sum of partials
  sum4_kernel<<<(M2 * NB / 4) / 256, 256, 0, stream>>>(
      outp, out, M2 * NB / 4);
  // 10) out row 4096 = A2[4096,:] @ t
  outrow_kernel<<<NB / 4, 256, 0, stream>>>(
      A2_b + (size_t)4096 * KP2, tT_b, out);
}

// Round 16
// 555.319 us; speedup vs baseline: 1.4032x; 1.4032x over previous
//
#include <hip/hip_runtime.h>

// ---- problem dims ----
#define IN_DIM 8193
#define OUT_DIM 4097
#define NB 1024
#define KP1 8256   // 129 * 64  (K for t = W4·x)
#define M2 4096    // t/out rows 0..4095; row 4096 handled separately
#define KP2 4160   // 65 * 64   (K for out = A·t)

typedef __attribute__((ext_vector_type(8))) short short8;
typedef __attribute__((ext_vector_type(4))) float f32x4;

__device__ __forceinline__ unsigned short f2bf(float f) {
  unsigned int u = __float_as_uint(f);
  u = (u + 0x7fffu + ((u >> 16) & 1u)) >> 16;  // RNE
  return (unsigned short)u;
}
__device__ __forceinline__ float bf2f(unsigned short u) {
  return __uint_as_float(((unsigned int)u) << 16);
}

// ---- pad + f32->bf16 convert (row-major -> row-major padded) ----
__global__ __launch_bounds__(256) void cvt_pad_kernel(
    const float* __restrict__ src, unsigned short* __restrict__ dst,
    int sR, int sC, int dR, int dC) {
  int gid = blockIdx.x * 256 + threadIdx.x;
  int i4 = gid * 4;
  if (i4 >= dR * dC) return;
  int r = i4 / dC;
  int c = i4 - r * dC;
  unsigned short o[4];
#pragma unroll
  for (int j = 0; j < 4; ++j) {
    int cc = c + j;
    float v = (r < sR && cc < sC) ? src[(size_t)r * sC + cc] : 0.f;
    o[j] = f2bf(v);
  }
  unsigned int lo = (unsigned)o[0] | ((unsigned)o[1] << 16);
  unsigned int hi = (unsigned)o[2] | ((unsigned)o[3] << 16);
  *reinterpret_cast<uint2*>(dst + i4) = make_uint2(lo, hi);
}

// ---- transpose+convert x -> xT bf16, FUSED hom row: zh[n] += Ainv[8192,:]·x[:,n] ----
__global__ __launch_bounds__(256) void transpose_cvt_zh_kernel(
    const float* __restrict__ src, unsigned short* __restrict__ dst,
    const float* __restrict__ arow, float* __restrict__ zh,
    int K, int N, int Kp) {
  __shared__ float tl[32][33];
  const int ntk = Kp >> 5;
  int bx = blockIdx.x % ntk;
  int by = blockIdx.x / ntk;
  int k0 = bx * 32, n0 = by * 32;
  int tx = threadIdx.x & 31, ty = threadIdx.x >> 5;
#pragma unroll
  for (int i = 0; i < 4; ++i) {
    int k = k0 + ty + i * 8;
    tl[ty + i * 8][tx] = (k < K) ? src[(size_t)k * N + n0 + tx] : 0.f;
  }
  const float av = (k0 + tx < K) ? arow[k0 + tx] : 0.f;
  __syncthreads();
#pragma unroll
  for (int i = 0; i < 4; ++i) {
    int n = n0 + ty + i * 8;
    float v = tl[tx][ty + i * 8];
    dst[(size_t)n * Kp + k0 + tx] = f2bf(v);
    float c = av * v;
#pragma unroll
    for (int m = 1; m <= 16; m <<= 1) c += __shfl_xor(c, m);
    if (tx == 0) atomicAdd(&zh[n], c);
  }
}

// ---- float4 zero ----
__global__ __launch_bounds__(256) void zero_kernel(float4* __restrict__ p, int n) {
  int i = blockIdx.x * 256 + threadIdx.x;
  if (i < n) p[i] = make_float4(0.f, 0.f, 0.f, 0.f);
}

// ---- W4 = T·Ainv build, v3: conv_lds structure over Ainv columns ----
// W4[r=(co,uo,vo), c] = sum_taps w[co,ci,kh,kw]·Ainv[(ci,2uo+kh,2vo+kw), c]
//                       + bias[co]·Ainv[8192, c]   (f32 math, ONE bf16 round)
// Block = (col-tile ct of 32, uo, vh). Slab 8ci x 3kh x 17vi x 32cols f32
// (55 KB) staged block-cooperatively (scalar dwords — Ainv row stride 8193
// breaks float4 alignment). Compute thread = (nl col, co-pair), acc[2][8]
// (~small VGPR; LDS-limited 2 blocks/CU -> 16 waves/CU of TLP). This is the
// R9-validated conv_lds kernel applied to Ainv's columns.
__global__ __launch_bounds__(256) void w4_build_kernel(
    const float* __restrict__ Ainv, const float* __restrict__ w,
    const float* __restrict__ bias, unsigned short* __restrict__ W4) {
  __shared__ float zl[24 * 18 * 32];
  __shared__ float wl[1152];
  __shared__ float bl[16];
  __shared__ float hl[32];
  const int b = blockIdx.x;          // 8256 = ct*32 + uo*2 + vh
  const int ct = b >> 5;
  const int sub = b & 31;
  const int uo = sub >> 1, vh = sub & 1;
  const int c0 = ct * 32;
  const int tid = threadIdx.x;
#pragma unroll
  for (int it = 0; it < 5; ++it) {
    const int i = it * 256 + tid;
    if (i < 1152) wl[i] = w[i];
  }
  if (tid < 16) bl[tid] = bias[tid];
  if (tid >= 32 && tid < 64) {
    const int c = c0 + tid - 32;
    hl[tid - 32] = (c < IN_DIM) ? Ainv[(size_t)8192 * IN_DIM + c] : 0.f;
  }
  const int nl4 = (tid & 7) * 4;
#pragma unroll
  for (int it = 0; it < 13; ++it) {
    const int R = it * 32 + (tid >> 3);
    if (R < 408) {
      const int ci = R / 51;
      const int rem = R - ci * 51;
      const int kh = rem / 17;
      const int vi = rem - kh * 17;
      const int u = 2 * uo + kh;
      const int v = vh * 16 + vi;
      float v4[4];
      const size_t base = (size_t)(ci * 1024 + u * 32 + v) * IN_DIM + c0 + nl4;
#pragma unroll
      for (int j = 0; j < 4; ++j) {
        const int c = c0 + nl4 + j;
        v4[j] = (u < 32 && v < 32 && c < IN_DIM) ? Ainv[base + j] : 0.f;
      }
#pragma unroll
      for (int j = 0; j < 4; ++j)
        zl[((ci * 3 + kh) * 18 + vi) * 32 + nl4 + j] = v4[j];
    }
  }
  __syncthreads();
  const int nl = tid & 31;
  const int cop = tid >> 5;
  const float hom = hl[nl];
  float acc[2][8];
#pragma unroll
  for (int c2 = 0; c2 < 2; ++c2) {
    const float bb = bl[cop + c2 * 8] * hom;
#pragma unroll
    for (int j = 0; j < 8; ++j) acc[c2][j] = bb;
  }
  for (int ci = 0; ci < 8; ++ci) {
#pragma unroll
    for (int kh = 0; kh < 3; ++kh) {
      const float* zr = zl + (ci * 3 + kh) * (18 * 32) + nl;
      float zv[17];
#pragma unroll
      for (int vi = 0; vi < 17; ++vi) zv[vi] = zr[vi * 32];
#pragma unroll
      for (int c2 = 0; c2 < 2; ++c2) {
        const int co = cop + c2 * 8;
        const float* wp = wl + ((co * 8 + ci) * 3 + kh) * 3;
#pragma unroll
        for (int kw = 0; kw < 3; ++kw) {
          const float wv = wp[kw];
#pragma unroll
          for (int j = 0; j < 8; ++j) acc[c2][j] += wv * zv[2 * j + kw];
        }
      }
    }
  }
  // write: r = co*256 + uo*16 + vh*8 + j ; col = c0 + nl (32 lanes = 64B)
#pragma unroll
  for (int c2 = 0; c2 < 2; ++c2) {
    const int co = cop + c2 * 8;
#pragma unroll
    for (int j = 0; j < 8; ++j) {
      const int r = co * 256 + uo * 16 + vh * 8 + j;
      W4[(size_t)r * KP1 + c0 + nl] = f2bf(acc[c2][j]);
    }
  }
}

// ---- 8-barrier 4-phase pipelined GEMM (R13-validated), 256 blocks ----
template <int NKT, int NSPLIT, int BMBITS, int MROWS>
__global__ __launch_bounds__(512) void gemm_dp(
    const unsigned short* __restrict__ Ab,
    const unsigned short* __restrict__ Bt,
    float* __restrict__ C, int Kp) {
  extern __shared__ unsigned short lds[];  // 8 * 8192 shorts = 128 KB
  const int tid = threadIdx.x;
  const int wid = tid >> 6;
  const int lane = tid & 63;
  const int b = blockIdx.x;
  const int x = b & 7, q = b >> 3;
  const int bm = (q & ((1 << BMBITS) - 1)) * 8 + x;
  const int bn = (q >> BMBITS) & 3;
  const int sp = q >> (BMBITS + 2);
  const int wm = (wid >> 2) << 7;  // 0 / 128
  const int wn = (wid & 3) << 6;   // 0 / 64 / 128 / 192

  const int qk = NKT / NSPLIT, rrk = NKT % NSPLIT;
  const int kt0 = sp * qk + (sp < rrk ? sp : rrk);
  const int T = qk + (sp < rrk ? 1 : 0);
  float* Cp = C + (size_t)sp * MROWS * NB;

  const int g0 = ((lane >> 4) ^ (lane & 7)) * 8;        // kk=0
  const int g1 = ((4 + (lane >> 4)) ^ (lane & 7)) * 8;  // kk=1
  const int alo = (lane & 15) * 64;
  const int bhalf = (wn >> 7) << 1;
  const int ahalf = (wid >> 2) << 1;
  const int bsub = ((wn & 64) << 6) + alo;

#define STAGEH(TT, ISA, H)                                                     \
  do {                                                                         \
    const int tt_ = (TT);                                                      \
    const int kc_ = kt0 + (tt_ < T - 1 ? tt_ : T - 1);                         \
    const int par_ = tt_ & 1;                                                  \
    const unsigned short* M_ = (ISA) ? Ab : Bt;                                \
    const int br_ = ((ISA) ? bm : bn) << 8;                                    \
    _Pragma("unroll")                                                          \
    for (int L_ = 0; L_ < 2; ++L_) {                                           \
      const int s_ = L_ * 512 + tid;                                           \
      const int row_ = s_ >> 3;                                                \
      const int gl_ = (s_ & 7) ^ (row_ & 7);                                   \
      const unsigned short* g_ = M_ + (size_t)(br_ + ((H) << 7) + row_) * Kp   \
                                    + (kc_ << 6) + gl_ * 8;                    \
      unsigned short* l_ = lds + (((ISA) ? 0 : 4) + ((H) << 1) + par_) * 8192  \
                               + (size_t)(L_ * 512 + wid * 64) * 8;            \
      __builtin_amdgcn_global_load_lds(                                        \
          (const __attribute__((address_space(1))) void*)g_,                   \
          (__attribute__((address_space(3))) void*)l_, 16, 0, 0);              \
    }                                                                          \
  } while (0)

#define MFMA16(BV0, BV1, NF0, NF1)                                             \
  do {                                                                         \
    __builtin_amdgcn_s_setprio(1);                                             \
    _Pragma("unroll")                                                          \
    for (int mf_ = 0; mf_ < 8; ++mf_) {                                        \
      asm volatile("v_mfma_f32_16x16x32_bf16 %0, %1, %2, %0"                   \
                   : "+v"(acc[mf_][NF0]) : "v"(af[mf_]), "v"(BV0));            \
      asm volatile("v_mfma_f32_16x16x32_bf16 %0, %1, %2, %0"                   \
                   : "+v"(acc[mf_][NF1]) : "v"(af[mf_]), "v"(BV1));            \
    }                                                                          \
    __builtin_amdgcn_s_setprio(0);                                             \
  } while (0)

#define PHASE_SYNC()                                                           \
  do {                                                                         \
    __builtin_amdgcn_s_barrier();                                              \
    asm volatile("s_waitcnt lgkmcnt(0)" ::: "memory");                         \
    __builtin_amdgcn_sched_barrier(0);                                         \
  } while (0)

  f32x4 acc[8][4];
#pragma unroll
  for (int i = 0; i < 8; ++i)
#pragma unroll
    for (int j = 0; j < 4; ++j) acc[i][j] = (f32x4)(0.0f);

  STAGEH(0, 1, 0); STAGEH(0, 1, 1);
  STAGEH(0, 0, 0); STAGEH(0, 0, 1);
  STAGEH(1, 1, 0); STAGEH(1, 1, 1);
  asm volatile("s_waitcnt vmcnt(4)" ::: "memory");
  __builtin_amdgcn_s_barrier();

  for (int t = 0; t < T; ++t) {
    const int par = t & 1;
    const unsigned short* Ab_ = lds + (ahalf + par) * 8192 + alo;
    const unsigned short* Bb_ = lds + (4 + bhalf + par) * 8192 + bsub;
    short8 af[8], b0, b1;
    // ---- Ph1 ----
    STAGEH(t + 1, 0, 0);
#pragma unroll
    for (int mf = 0; mf < 8; ++mf)
      af[mf] = *reinterpret_cast<const short8*>(Ab_ + mf * 1024 + g0);
    b0 = *reinterpret_cast<const short8*>(Bb_ + 0 * 1024 + g0);
    b1 = *reinterpret_cast<const short8*>(Bb_ + 1 * 1024 + g0);
    PHASE_SYNC();
    MFMA16(b0, b1, 0, 1);
    __builtin_amdgcn_s_barrier();
    // ---- Ph2 ----
    STAGEH(t + 1, 0, 1);
    b0 = *reinterpret_cast<const short8*>(Bb_ + 2 * 1024 + g0);
    b1 = *reinterpret_cast<const short8*>(Bb_ + 3 * 1024 + g0);
    PHASE_SYNC();
    MFMA16(b0, b1, 2, 3);
    __builtin_amdgcn_s_barrier();
    // ---- Ph3 ----
#pragma unroll
    for (int mf = 0; mf < 8; ++mf)
      af[mf] = *reinterpret_cast<const short8*>(Ab_ + mf * 1024 + g1);
    b0 = *reinterpret_cast<const short8*>(Bb_ + 2 * 1024 + g1);
    b1 = *reinterpret_cast<const short8*>(Bb_ + 3 * 1024 + g1);
    PHASE_SYNC();
    MFMA16(b0, b1, 2, 3);
    __builtin_amdgcn_s_barrier();
    // ---- Ph4 ----
    STAGEH(t + 2, 1, 0); STAGEH(t + 2, 1, 1);
    b0 = *reinterpret_cast<const short8*>(Bb_ + 0 * 1024 + g1);
    b1 = *reinterpret_cast<const short8*>(Bb_ + 1 * 1024 + g1);
    asm volatile("s_waitcnt vmcnt(4)" ::: "memory");
    PHASE_SYNC();
    MFMA16(b0, b1, 0, 1);
    __builtin_amdgcn_s_barrier();
  }
#undef STAGEH
#undef MFMA16
#undef PHASE_SYNC

#pragma unroll
  for (int mf = 0; mf < 8; ++mf) {
    const int rb = (bm << 8) + wm + mf * 16 + ((lane >> 4) << 2);
#pragma unroll
    for (int nf = 0; nf < 4; ++nf) {
      const int col = (bn << 8) + wn + nf * 16 + (lane & 15);
#pragma unroll
      for (int r = 0; r < 4; ++r)
        Cp[(size_t)(rb + r) * NB + col] = acc[mf][nf][r];
    }
  }
}

// ---- sum 4 t-partials + transpose + cvt -> tT rows 0..4095 ----
__global__ __launch_bounds__(256) void sum4t_kernel(
    const float* __restrict__ tp, unsigned short* __restrict__ tT) {
  __shared__ float tl[32][33];
  const int nr = M2 / 32;           // 128 r-tiles
  const int br = blockIdx.x % nr;
  const int bn = blockIdx.x / nr;   // 32 n-tiles
  const int r0 = br * 32, n0 = bn * 32;
  const int tx = threadIdx.x & 31, ty = threadIdx.x >> 5;
  const size_t S = (size_t)M2 * NB;
#pragma unroll
  for (int i = 0; i < 4; ++i) {
    const int r = r0 + ty + i * 8;
    const size_t g = (size_t)r * NB + n0 + tx;
    tl[ty + i * 8][tx] = (tp[g] + tp[g + S]) + (tp[g + 2 * S] + tp[g + 3 * S]);
  }
  __syncthreads();
#pragma unroll
  for (int i = 0; i < 4; ++i) {
    const int n = n0 + ty + i * 8;
    tT[(size_t)n * KP2 + r0 + tx] = f2bf(tl[tx][ty + i * 8]);
  }
}

// ---- tT rows 4096..4159: hom row + zero pad ----
__global__ __launch_bounds__(256) void homrow_kernel(
    const float* __restrict__ zh, unsigned short* __restrict__ tT) {
  const int n = blockIdx.x * 256 + threadIdx.x;
  unsigned short* p = tT + (size_t)n * KP2 + 4096;
  uint4 z4 = make_uint4(0u, 0u, 0u, 0u);
  uint4 h4 = z4;
  h4.x = (unsigned)f2bf(zh[n]);
  *reinterpret_cast<uint4*>(p) = h4;
#pragma unroll
  for (int i = 1; i < 8; ++i) *reinterpret_cast<uint4*>(p + i * 8) = z4;
}

// ---- final sum of 4 split-K partials -> d_out rows 0..4095 ----
__global__ __launch_bounds__(256) void sum4_kernel(
    const float* __restrict__ p, float* __restrict__ out, int n4) {
  const int i = blockIdx.x * 256 + threadIdx.x;
  if (i >= n4) return;
  const size_t stride4 = (size_t)M2 * NB / 4;
  const float4* p4 = (const float4*)p;
  float4 a = p4[i];
  float4 b = p4[i + stride4];
  float4 c = p4[i + 2 * stride4];
  float4 d = p4[i + 3 * stride4];
  float4 r;
  r.x = (a.x + b.x) + (c.x + d.x);
  r.y = (a.y + b.y) + (c.y + d.y);
  r.z = (a.z + b.z) + (c.z + d.z);
  r.w = (a.w + b.w) + (c.w + d.w);
  reinterpret_cast<float4*>(out)[i] = r;
}

// ---- out row 4096: wave-per-column dot over bf16 A2 row x tT ----
__global__ __launch_bounds__(256) void outrow_kernel(
    const unsigned short* __restrict__ A2row,
    const unsigned short* __restrict__ tT, float* __restrict__ out) {
  const int wid = threadIdx.x >> 6, lane = threadIdx.x & 63;
  const int n = blockIdx.x * 4 + wid;
  const unsigned short* trow = tT + (size_t)n * KP2;
  float acc = 0.f;
#pragma unroll
  for (int it = 0; it < 9; ++it) {
    const int i8 = it * 64 + lane;
    if (i8 < KP2 / 8) {
      short8 tv = *reinterpret_cast<const short8*>(trow + i8 * 8);
      short8 av = *reinterpret_cast<const short8*>(A2row + i8 * 8);
#pragma unroll
      for (int j = 0; j < 8; ++j)
        acc += bf2f((unsigned short)tv[j]) * bf2f((unsigned short)av[j]);
    }
  }
#pragma unroll
  for (int m = 1; m <= 32; m <<= 1) acc += __shfl_xor(acc, m);
  if (lane == 0) out[(size_t)4096 * NB + n] = acc;
}

extern "C" void kernel_launch(void* const* d_in, const int* in_sizes, int n_in,
                              void* d_out, int out_size, void* d_ws, size_t ws_size,
                              hipStream_t stream) {
  const float* w    = (const float*)d_in[0];  // (16,8,3,3)
  const float* bias = (const float*)d_in[1];  // (16,)
  const float* A    = (const float*)d_in[2];  // (4097,4097)
  const float* Ainv = (const float*)d_in[3];  // (8193,8193)
  const float* x    = (const float*)d_in[4];  // (8193,1024)
  float* out = (float*)d_out;                 // (4097,1024)

  // Workspace (160.2 MB):
  //   [0]      W4 4096xKP1 bf16 = 67.6 MB (dead after GEMM_t; outp 67.1 aliases)
  //   [67.6]   xT_b 1024xKP1 bf16 = 16.9 MB
  //   [84.5]   tp 4x4096x1024 f32 = 67.1 MB (dead after sum4t; A2_b 34.1 aliases)
  //   [151.6]  tT_b 1024xKP2 bf16 = 8.5 MB
  //   [160.1]  zh 1024 f32
  char* ws = (char*)d_ws;
  const size_t o_xT = (size_t)M2 * KP1 * 2;
  const size_t o_tp = o_xT + (size_t)NB * KP1 * 2;
  const size_t o_tT = o_tp + (size_t)4 * M2 * NB * 4;
  const size_t o_zh = o_tT + (size_t)NB * KP2 * 2;
  unsigned short* W4   = (unsigned short*)ws;
  unsigned short* xT_b = (unsigned short*)(ws + o_xT);
  float*          tp   = (float*)(ws + o_tp);
  unsigned short* tT_b = (unsigned short*)(ws + o_tT);
  float*          zh   = (float*)(ws + o_zh);
  unsigned short* A2_b = (unsigned short*)(ws + o_tp);  // aliases tp
  float*          outp = (float*)ws;                    // aliases W4
  (void)ws_size; (void)in_sizes; (void)n_in; (void)out_size;

  hipFuncSetAttribute((const void*)gemm_dp<129, 4, 1, M2>,
                      hipFuncAttributeMaxDynamicSharedMemorySize, 131072);
  hipFuncSetAttribute((const void*)gemm_dp<65, 4, 1, M2>,
                      hipFuncAttributeMaxDynamicSharedMemorySize, 131072);

  // 1) zero zh
  zero_kernel<<<1, 256, 0, stream>>>((float4*)zh, 256);
  // 2) x -> x^T bf16 + fused zh = Ainv[8192,:] @ x
  transpose_cvt_zh_kernel<<<(KP1 / 32) * (NB / 32), 256, 0, stream>>>(
      x, xT_b, Ainv + (size_t)8192 * IN_DIM, zh, IN_DIM, NB, KP1);
  // 3) W4 = T·Ainv (bias folded), bf16 padded (4096 x KP1), conv_lds-style
  w4_build_kernel<<<8256, 256, 0, stream>>>(Ainv, w, bias, W4);
  // 4) tp[0..3] = W4 @ x  (4-phase GEMM, split-K=4, exactly 256 blocks)
  gemm_dp<129, 4, 1, M2><<<256, 512, 131072, stream>>>(
      W4, xT_b, tp, KP1);
  // 5) t^T rows 0..4095 = sum partials + transpose + cvt
  sum4t_kernel<<<(M2 / 32) * (NB / 32), 256, 0, stream>>>(tp, tT_b);
  // 6) t^T rows 4096..4159 = hom + zero pad
  homrow_kernel<<<4, 256, 0, stream>>>(zh, tT_b);
  // 7) A rows 0..4096 -> padded bf16 (aliases dead tp)
  cvt_pad_kernel<<<(OUT_DIM * KP2 / 4 + 255) / 256, 256, 0, stream>>>(
      A, A2_b, OUT_DIM, OUT_DIM, OUT_DIM, KP2);
  // 8) outp[0..3] = A @ t  (4-phase GEMM, split-K=4; outp aliases dead W4)
  gemm_dp<65, 4, 1, M2><<<256, 512, 131072, stream>>>(
      A2_b, tT_b, outp, KP2);
  // 9) out rows 0..4095 = sum of partials
  sum4_kernel<<<(M2 * NB / 4) / 256, 256, 0, stream>>>(
      outp, out, M2 * NB / 4);
  // 10) out row 4096 = A2[4096,:] @ t
  outrow_kernel<<<NB / 4, 256, 0, stream>>>(
      A2_b + (size_t)4096 * KP2, tT_b, out);
}

// Round 17
// 486.450 us; speedup vs baseline: 1.6018x; 1.1416x over previous
//
#include <hip/hip_runtime.h>

// ---- problem dims ----
#define IN_DIM 8193
#define OUT_DIM 4097
#define NB 1024
#define M1 8192    // GEMM1 M (rows 0..8191; row 8192 = hom handled separately)
#define KP1 8256   // 129 * 64
#define M2 4096    // GEMM2 M (row 4096 handled separately)
#define KP2 4160   // 65 * 64

typedef __attribute__((ext_vector_type(8))) short short8;
typedef __attribute__((ext_vector_type(4))) float f32x4;

__device__ __forceinline__ unsigned short f2bf(float f) {
  unsigned int u = __float_as_uint(f);
  u = (u + 0x7fffu + ((u >> 16) & 1u)) >> 16;  // RNE
  return (unsigned short)u;
}
__device__ __forceinline__ float bf2f(unsigned short u) {
  return __uint_as_float(((unsigned int)u) << 16);
}

// ---- pad + f32->bf16 convert (row-major -> row-major padded) ----
__global__ __launch_bounds__(256) void cvt_pad_kernel(
    const float* __restrict__ src, unsigned short* __restrict__ dst,
    int sR, int sC, int dR, int dC) {
  int gid = blockIdx.x * 256 + threadIdx.x;
  int i4 = gid * 4;
  if (i4 >= dR * dC) return;
  int r = i4 / dC;
  int c = i4 - r * dC;
  unsigned short o[4];
#pragma unroll
  for (int j = 0; j < 4; ++j) {
    int cc = c + j;
    float v = (r < sR && cc < sC) ? src[(size_t)r * sC + cc] : 0.f;
    o[j] = f2bf(v);
  }
  unsigned int lo = (unsigned)o[0] | ((unsigned)o[1] << 16);
  unsigned int hi = (unsigned)o[2] | ((unsigned)o[3] << 16);
  *reinterpret_cast<uint2*>(dst + i4) = make_uint2(lo, hi);
}

// ---- transpose+convert x -> xT bf16, FUSED hom row: zh[n] += Ainv[8192,:]·x[:,n] ----
__global__ __launch_bounds__(256) void transpose_cvt_zh_kernel(
    const float* __restrict__ src, unsigned short* __restrict__ dst,
    const float* __restrict__ arow, float* __restrict__ zh,
    int K, int N, int Kp) {
  __shared__ float tl[32][33];
  const int ntk = Kp >> 5;
  int bx = blockIdx.x % ntk;
  int by = blockIdx.x / ntk;
  int k0 = bx * 32, n0 = by * 32;
  int tx = threadIdx.x & 31, ty = threadIdx.x >> 5;
#pragma unroll
  for (int i = 0; i < 4; ++i) {
    int k = k0 + ty + i * 8;
    tl[ty + i * 8][tx] = (k < K) ? src[(size_t)k * N + n0 + tx] : 0.f;
  }
  const float av = (k0 + tx < K) ? arow[k0 + tx] : 0.f;
  __syncthreads();
#pragma unroll
  for (int i = 0; i < 4; ++i) {
    int n = n0 + ty + i * 8;
    float v = tl[tx][ty + i * 8];
    dst[(size_t)n * Kp + k0 + tx] = f2bf(v);
    float c = av * v;
#pragma unroll
    for (int m = 1; m <= 16; m <<= 1) c += __shfl_xor(c, m);
    if (tx == 0) atomicAdd(&zh[n], c);
  }
}

// ---- float4 zero ----
__global__ __launch_bounds__(256) void zero_kernel(float4* __restrict__ p, int n) {
  int i = blockIdx.x * 256 + threadIdx.x;
  if (i < n) p[i] = make_float4(0.f, 0.f, 0.f, 0.f);
}

// ---- 8-barrier 4-phase pipelined GEMM (R13-validated), 256 blocks ----
// ATOMIC epilogue: C += acc via unsafeAtomicAdd (pre-zeroed C; split-K
// partials merge in HBM — R7-validated pattern, order-independent to ulp).
template <int NKT, int NSPLIT, int BMBITS, int MROWS>
__global__ __launch_bounds__(512) void gemm_dp(
    const unsigned short* __restrict__ Ab,
    const unsigned short* __restrict__ Bt,
    float* __restrict__ C, int Kp) {
  extern __shared__ unsigned short lds[];  // 8 * 8192 shorts = 128 KB
  const int tid = threadIdx.x;
  const int wid = tid >> 6;
  const int lane = tid & 63;
  const int b = blockIdx.x;
  const int x = b & 7, q = b >> 3;
  const int bm = (q & ((1 << BMBITS) - 1)) * 8 + x;
  const int bn = (q >> BMBITS) & 3;
  const int sp = q >> (BMBITS + 2);
  const int wm = (wid >> 2) << 7;  // 0 / 128
  const int wn = (wid & 3) << 6;   // 0 / 64 / 128 / 192

  const int qk = NKT / NSPLIT, rrk = NKT % NSPLIT;
  const int kt0 = sp * qk + (sp < rrk ? sp : rrk);
  const int T = qk + (sp < rrk ? 1 : 0);

  const int g0 = ((lane >> 4) ^ (lane & 7)) * 8;        // kk=0
  const int g1 = ((4 + (lane >> 4)) ^ (lane & 7)) * 8;  // kk=1
  const int alo = (lane & 15) * 64;
  const int bhalf = (wn >> 7) << 1;
  const int ahalf = (wid >> 2) << 1;
  const int bsub = ((wn & 64) << 6) + alo;

#define STAGEH(TT, ISA, H)                                                     \
  do {                                                                         \
    const int tt_ = (TT);                                                      \
    const int kc_ = kt0 + (tt_ < T - 1 ? tt_ : T - 1);                         \
    const int par_ = tt_ & 1;                                                  \
    const unsigned short* M_ = (ISA) ? Ab : Bt;                                \
    const int br_ = ((ISA) ? bm : bn) << 8;                                    \
    _Pragma("unroll")                                                          \
    for (int L_ = 0; L_ < 2; ++L_) {                                           \
      const int s_ = L_ * 512 + tid;                                           \
      const int row_ = s_ >> 3;                                                \
      const int gl_ = (s_ & 7) ^ (row_ & 7);                                   \
      const unsigned short* g_ = M_ + (size_t)(br_ + ((H) << 7) + row_) * Kp   \
                                    + (kc_ << 6) + gl_ * 8;                    \
      unsigned short* l_ = lds + (((ISA) ? 0 : 4) + ((H) << 1) + par_) * 8192  \
                               + (size_t)(L_ * 512 + wid * 64) * 8;            \
      __builtin_amdgcn_global_load_lds(                                        \
          (const __attribute__((address_space(1))) void*)g_,                   \
          (__attribute__((address_space(3))) void*)l_, 16, 0, 0);              \
    }                                                                          \
  } while (0)

#define MFMA16(BV0, BV1, NF0, NF1)                                             \
  do {                                                                         \
    __builtin_amdgcn_s_setprio(1);                                             \
    _Pragma("unroll")                                                          \
    for (int mf_ = 0; mf_ < 8; ++mf_) {                                        \
      asm volatile("v_mfma_f32_16x16x32_bf16 %0, %1, %2, %0"                   \
                   : "+v"(acc[mf_][NF0]) : "v"(af[mf_]), "v"(BV0));            \
      asm volatile("v_mfma_f32_16x16x32_bf16 %0, %1, %2, %0"                   \
                   : "+v"(acc[mf_][NF1]) : "v"(af[mf_]), "v"(BV1));            \
    }                                                                          \
    __builtin_amdgcn_s_setprio(0);                                             \
  } while (0)

#define PHASE_SYNC()                                                           \
  do {                                                                         \
    __builtin_amdgcn_s_barrier();                                              \
    asm volatile("s_waitcnt lgkmcnt(0)" ::: "memory");                         \
    __builtin_amdgcn_sched_barrier(0);                                         \
  } while (0)

  f32x4 acc[8][4];
#pragma unroll
  for (int i = 0; i < 8; ++i)
#pragma unroll
    for (int j = 0; j < 4; ++j) acc[i][j] = (f32x4)(0.0f);

  STAGEH(0, 1, 0); STAGEH(0, 1, 1);
  STAGEH(0, 0, 0); STAGEH(0, 0, 1);
  STAGEH(1, 1, 0); STAGEH(1, 1, 1);
  asm volatile("s_waitcnt vmcnt(4)" ::: "memory");
  __builtin_amdgcn_s_barrier();

  for (int t = 0; t < T; ++t) {
    const int par = t & 1;
    const unsigned short* Ab_ = lds + (ahalf + par) * 8192 + alo;
    const unsigned short* Bb_ = lds + (4 + bhalf + par) * 8192 + bsub;
    short8 af[8], b0, b1;
    // ---- Ph1 ----
    STAGEH(t + 1, 0, 0);
#pragma unroll
    for (int mf = 0; mf < 8; ++mf)
      af[mf] = *reinterpret_cast<const short8*>(Ab_ + mf * 1024 + g0);
    b0 = *reinterpret_cast<const short8*>(Bb_ + 0 * 1024 + g0);
    b1 = *reinterpret_cast<const short8*>(Bb_ + 1 * 1024 + g0);
    PHASE_SYNC();
    MFMA16(b0, b1, 0, 1);
    __builtin_amdgcn_s_barrier();
    // ---- Ph2 ----
    STAGEH(t + 1, 0, 1);
    b0 = *reinterpret_cast<const short8*>(Bb_ + 2 * 1024 + g0);
    b1 = *reinterpret_cast<const short8*>(Bb_ + 3 * 1024 + g0);
    PHASE_SYNC();
    MFMA16(b0, b1, 2, 3);
    __builtin_amdgcn_s_barrier();
    // ---- Ph3 ----
#pragma unroll
    for (int mf = 0; mf < 8; ++mf)
      af[mf] = *reinterpret_cast<const short8*>(Ab_ + mf * 1024 + g1);
    b0 = *reinterpret_cast<const short8*>(Bb_ + 2 * 1024 + g1);
    b1 = *reinterpret_cast<const short8*>(Bb_ + 3 * 1024 + g1);
    PHASE_SYNC();
    MFMA16(b0, b1, 2, 3);
    __builtin_amdgcn_s_barrier();
    // ---- Ph4 ----
    STAGEH(t + 2, 1, 0); STAGEH(t + 2, 1, 1);
    b0 = *reinterpret_cast<const short8*>(Bb_ + 0 * 1024 + g1);
    b1 = *reinterpret_cast<const short8*>(Bb_ + 1 * 1024 + g1);
    asm volatile("s_waitcnt vmcnt(4)" ::: "memory");
    PHASE_SYNC();
    MFMA16(b0, b1, 0, 1);
    __builtin_amdgcn_s_barrier();
  }
#undef STAGEH
#undef MFMA16
#undef PHASE_SYNC

  // epilogue: C/D layout col=lane&15, row=(lane>>4)*4+reg; atomic merge
#pragma unroll
  for (int mf = 0; mf < 8; ++mf) {
    const int rb = (bm << 8) + wm + mf * 16 + ((lane >> 4) << 2);
#pragma unroll
    for (int nf = 0; nf < 4; ++nf) {
      const int col = (bn << 8) + wn + nf * 16 + (lane & 15);
#pragma unroll
      for (int r = 0; r < 4; ++r)
        unsafeAtomicAdd(&C[(size_t)(rb + r) * NB + col], acc[mf][nf][r]);
    }
  }
}

// ---- LDS-tiled conv (R9-validated, single-z): block = (uo, vh, 32-n) ----
__global__ __launch_bounds__(256) void conv_lds_kernel(
    const float* __restrict__ za, const float* __restrict__ zh,
    const float* __restrict__ w, const float* __restrict__ bias,
    unsigned short* __restrict__ tT) {
  __shared__ float zl[24 * 18 * 32];
  __shared__ float wl[1152];
  __shared__ float bl[16];
  const int b = blockIdx.x;
  const int nt = b & 31, vh = (b >> 5) & 1, uo = b >> 6;
  const int n0 = nt * 32;
  const int tid = threadIdx.x;
#pragma unroll
  for (int it = 0; it < 5; ++it) {
    const int idx = it * 256 + tid;
    if (idx < 1152) wl[idx] = w[idx];
  }
  if (tid < 16) bl[tid] = bias[tid];
  const int nl4 = (tid & 7) * 4;
#pragma unroll
  for (int it = 0; it < 13; ++it) {
    const int R = it * 32 + (tid >> 3);
    if (R < 408) {
      const int ci = R / 51;
      const int rem = R - ci * 51;
      const int kh = rem / 17;
      const int vi = rem - kh * 17;
      const int u = 2 * uo + kh;
      const int v = vh * 16 + vi;
      float4 val = make_float4(0.f, 0.f, 0.f, 0.f);
      if (u < 32 && v < 32) {
        const size_t g = ((size_t)(ci * 1024 + u * 32 + v)) * 1024 + n0 + nl4;
        val = *reinterpret_cast<const float4*>(za + g);
      }
      *reinterpret_cast<float4*>(zl + ((ci * 3 + kh) * 18 + vi) * 32 + nl4) = val;
    }
  }
  __syncthreads();
  const int nl = tid & 31;
  const int cop = tid >> 5;
  const float hom = zh[n0 + nl];
  float acc[2][8];
#pragma unroll
  for (int c = 0; c < 2; ++c) {
    const float bb = bl[cop + c * 8] * hom;
#pragma unroll
    for (int vo = 0; vo < 8; ++vo) acc[c][vo] = bb;
  }
  for (int ci = 0; ci < 8; ++ci) {
#pragma unroll
    for (int kh = 0; kh < 3; ++kh) {
      const float* zr = zl + (ci * 3 + kh) * (18 * 32) + nl;
      float zv[17];
#pragma unroll
      for (int vi = 0; vi < 17; ++vi) zv[vi] = zr[vi * 32];
#pragma unroll
      for (int c = 0; c < 2; ++c) {
        const int co = cop + c * 8;
        const float* wp = wl + ((co * 8 + ci) * 3 + kh) * 3;
#pragma unroll
        for (int kw = 0; kw < 3; ++kw) {
          const float wv = wp[kw];
#pragma unroll
          for (int vo = 0; vo < 8; ++vo) acc[c][vo] += wv * zv[2 * vo + kw];
        }
      }
    }
  }
#pragma unroll
  for (int c = 0; c < 2; ++c) {
    const int co = cop + c * 8;
    unsigned short o[8];
#pragma unroll
    for (int vo = 0; vo < 8; ++vo) o[vo] = f2bf(acc[c][vo]);
    uint4 pv;
    pv.x = (unsigned)o[0] | ((unsigned)o[1] << 16);
    pv.y = (unsigned)o[2] | ((unsigned)o[3] << 16);
    pv.z = (unsigned)o[4] | ((unsigned)o[5] << 16);
    pv.w = (unsigned)o[6] | ((unsigned)o[7] << 16);
    *reinterpret_cast<uint4*>(
        tT + (size_t)(n0 + nl) * KP2 + co * 256 + uo * 16 + vh * 8) = pv;
  }
}

// ---- tT rows 4096..4159: hom row + zero pad ----
__global__ __launch_bounds__(256) void homrow_kernel(
    const float* __restrict__ zh, unsigned short* __restrict__ tT) {
  const int n = blockIdx.x * 256 + threadIdx.x;
  unsigned short* p = tT + (size_t)n * KP2 + 4096;
  uint4 z4 = make_uint4(0u, 0u, 0u, 0u);
  uint4 h4 = z4;
  h4.x = (unsigned)f2bf(zh[n]);
  *reinterpret_cast<uint4*>(p) = h4;
#pragma unroll
  for (int i = 1; i < 8; ++i) *reinterpret_cast<uint4*>(p + i * 8) = z4;
}

// ---- out row 4096: wave-per-column dot over bf16 A2 row x tT ----
__global__ __launch_bounds__(256) void outrow_kernel(
    const unsigned short* __restrict__ A2row,
    const unsigned short* __restrict__ tT, float* __restrict__ out) {
  const int wid = threadIdx.x >> 6, lane = threadIdx.x & 63;
  const int n = blockIdx.x * 4 + wid;
  const unsigned short* trow = tT + (size_t)n * KP2;
  float acc = 0.f;
#pragma unroll
  for (int it = 0; it < 9; ++it) {
    const int i8 = it * 64 + lane;
    if (i8 < KP2 / 8) {
      short8 tv = *reinterpret_cast<const short8*>(trow + i8 * 8);
      short8 av = *reinterpret_cast<const short8*>(A2row + i8 * 8);
#pragma unroll
      for (int j = 0; j < 8; ++j)
        acc += bf2f((unsigned short)tv[j]) * bf2f((unsigned short)av[j]);
    }
  }
#pragma unroll
  for (int m = 1; m <= 32; m <<= 1) acc += __shfl_xor(acc, m);
  if (lane == 0) out[(size_t)4096 * NB + n] = acc;
}

extern "C" void kernel_launch(void* const* d_in, const int* in_sizes, int n_in,
                              void* d_out, int out_size, void* d_ws, size_t ws_size,
                              hipStream_t stream) {
  const float* w    = (const float*)d_in[0];  // (16,8,3,3)
  const float* bias = (const float*)d_in[1];  // (16,)
  const float* A    = (const float*)d_in[2];  // (4097,4097)
  const float* Ainv = (const float*)d_in[3];  // (8193,8193)
  const float* x    = (const float*)d_in[4];  // (8193,1024)
  float* out = (float*)d_out;                 // (4097,1024)

  // Workspace (194.3 MB <= proven 231.5):
  //   [0]       Ainv_b 8192xKP1 bf16 = 135.27 MB (dead after GEMM1;
  //             A2_b 34.09 MB aliases it)
  //   [135.27]  xT_b 1024xKP1 bf16 = 16.91 MB
  //   [152.17]  z 8192x1024 f32 = 33.55 MB (atomic split-K merge target)
  //   [185.73]  tT_b 1024xKP2 bf16 = 8.52 MB
  //   [194.25]  zh 1024 f32
  char* ws = (char*)d_ws;
  const size_t o_xT = (size_t)M1 * KP1 * 2;
  const size_t o_z  = o_xT + (size_t)NB * KP1 * 2;
  const size_t o_tT = o_z + (size_t)M1 * NB * 4;
  const size_t o_zh = o_tT + (size_t)NB * KP2 * 2;
  unsigned short* Ainv_b = (unsigned short*)ws;
  unsigned short* xT_b   = (unsigned short*)(ws + o_xT);
  float*          z      = (float*)(ws + o_z);
  unsigned short* tT_b   = (unsigned short*)(ws + o_tT);
  float*          zh     = (float*)(ws + o_zh);
  unsigned short* A2_b   = (unsigned short*)ws;
  (void)ws_size; (void)in_sizes; (void)n_in; (void)out_size;

  hipFuncSetAttribute((const void*)gemm_dp<129, 2, 2, M1>,
                      hipFuncAttributeMaxDynamicSharedMemorySize, 131072);
  hipFuncSetAttribute((const void*)gemm_dp<65, 4, 1, M2>,
                      hipFuncAttributeMaxDynamicSharedMemorySize, 131072);

  // 1) zero zh + z (atomic targets)
  zero_kernel<<<1, 256, 0, stream>>>((float4*)zh, 256);
  zero_kernel<<<(M1 * NB / 4) / 256, 256, 0, stream>>>(
      (float4*)z, M1 * NB / 4);
  // 2) Ainv rows 0..8191 -> padded bf16
  cvt_pad_kernel<<<(M1 * KP1 / 4) / 256, 256, 0, stream>>>(
      Ainv, Ainv_b, IN_DIM, IN_DIM, M1, KP1);
  // 3) x -> x^T bf16 + fused zh = Ainv[8192,:] @ x
  transpose_cvt_zh_kernel<<<(KP1 / 32) * (NB / 32), 256, 0, stream>>>(
      x, xT_b, Ainv + (size_t)8192 * IN_DIM, zh, IN_DIM, NB, KP1);
  // 4) z += Ainv @ x  (4-phase GEMM, split-K=2 atomic, exactly 256 blocks)
  gemm_dp<129, 2, 2, M1><<<256, 512, 131072, stream>>>(
      Ainv_b, xT_b, z, KP1);
  // 5) t^T rows 0..4095 = conv(z, hom=zh)  (LDS-tiled, 1024 blocks)
  conv_lds_kernel<<<1024, 256, 0, stream>>>(z, zh, w, bias, tT_b);
  // 5b) t^T rows 4096..4159 = hom + zero pad
  homrow_kernel<<<4, 256, 0, stream>>>(zh, tT_b);
  // 6) A rows 0..4096 -> padded bf16 (aliases dead Ainv_b)
  cvt_pad_kernel<<<(OUT_DIM * KP2 / 4 + 255) / 256, 256, 0, stream>>>(
      A, A2_b, OUT_DIM, OUT_DIM, OUT_DIM, KP2);
  // 7) zero out rows 0..4095; out += A @ t (split-K=4 atomic, 256 blocks)
  zero_kernel<<<(M2 * NB / 4) / 256, 256, 0, stream>>>(
      (float4*)out, M2 * NB / 4);
  gemm_dp<65, 4, 1, M2><<<256, 512, 131072, stream>>>(
      A2_b, tT_b, out, KP2);
  // 8) out row 4096 = A2[4096,:] @ t
  outrow_kernel<<<NB / 4, 256, 0, stream>>>(
      A2_b + (size_t)4096 * KP2, tT_b, out);
}

// Round 18
// 412.937 us; speedup vs baseline: 1.8870x; 1.1780x over previous
//
#include <hip/hip_runtime.h>

// ---- problem dims ----
#define IN_DIM 8193
#define OUT_DIM 4097
#define NB 1024
#define M1 8192    // GEMM1 M (rows 0..8191; row 8192 = hom handled separately)
#define KP1 8256   // 129 * 64
#define M2 4096    // GEMM2 M (row 4096 handled separately)
#define KP2 4160   // 65 * 64

typedef __attribute__((ext_vector_type(8))) short short8;
typedef __attribute__((ext_vector_type(4))) float f32x4;

__device__ __forceinline__ unsigned short f2bf(float f) {
  unsigned int u = __float_as_uint(f);
  u = (u + 0x7fffu + ((u >> 16) & 1u)) >> 16;  // RNE
  return (unsigned short)u;
}
__device__ __forceinline__ float bf2f(unsigned short u) {
  return __uint_as_float(((unsigned int)u) << 16);
}

// ---- pad + f32->bf16 convert (row-major -> row-major padded) ----
__global__ __launch_bounds__(256) void cvt_pad_kernel(
    const float* __restrict__ src, unsigned short* __restrict__ dst,
    int sR, int sC, int dR, int dC) {
  int gid = blockIdx.x * 256 + threadIdx.x;
  int i4 = gid * 4;
  if (i4 >= dR * dC) return;
  int r = i4 / dC;
  int c = i4 - r * dC;
  unsigned short o[4];
#pragma unroll
  for (int j = 0; j < 4; ++j) {
    int cc = c + j;
    float v = (r < sR && cc < sC) ? src[(size_t)r * sC + cc] : 0.f;
    o[j] = f2bf(v);
  }
  unsigned int lo = (unsigned)o[0] | ((unsigned)o[1] << 16);
  unsigned int hi = (unsigned)o[2] | ((unsigned)o[3] << 16);
  *reinterpret_cast<uint2*>(dst + i4) = make_uint2(lo, hi);
}

// ---- transpose+convert x -> xT bf16, FUSED hom row: zh[n] += Ainv[8192,:]·x[:,n] ----
__global__ __launch_bounds__(256) void transpose_cvt_zh_kernel(
    const float* __restrict__ src, unsigned short* __restrict__ dst,
    const float* __restrict__ arow, float* __restrict__ zh,
    int K, int N, int Kp) {
  __shared__ float tl[32][33];
  const int ntk = Kp >> 5;
  int bx = blockIdx.x % ntk;
  int by = blockIdx.x / ntk;
  int k0 = bx * 32, n0 = by * 32;
  int tx = threadIdx.x & 31, ty = threadIdx.x >> 5;
#pragma unroll
  for (int i = 0; i < 4; ++i) {
    int k = k0 + ty + i * 8;
    tl[ty + i * 8][tx] = (k < K) ? src[(size_t)k * N + n0 + tx] : 0.f;
  }
  const float av = (k0 + tx < K) ? arow[k0 + tx] : 0.f;
  __syncthreads();
#pragma unroll
  for (int i = 0; i < 4; ++i) {
    int n = n0 + ty + i * 8;
    float v = tl[tx][ty + i * 8];
    dst[(size_t)n * Kp + k0 + tx] = f2bf(v);
    float c = av * v;
#pragma unroll
    for (int m = 1; m <= 16; m <<= 1) c += __shfl_xor(c, m);
    if (tx == 0) atomicAdd(&zh[n], c);
  }
}

// ---- float4 zero ----
__global__ __launch_bounds__(256) void zero_kernel(float4* __restrict__ p, int n) {
  int i = blockIdx.x * 256 + threadIdx.x;
  if (i < n) p[i] = make_float4(0.f, 0.f, 0.f, 0.f);
}

// ---- 8-barrier 4-phase pipelined GEMM (R13-validated), 256 blocks ----
// Cpart(sp) (MROWS x NB) = A(256-tile bm) * Bt(256-tile bn)^T over kt range.
// Tile 256x256, BK=64, 8 waves (2M x 4N), per-wave 128x64.
// LDS = 8 half-slots x 16KB (A/B x half x parity). Per K-tile, 4 quadrant
// phases, each {stage half-tile; ds_reads; s_barrier; lgkmcnt(0);
// sched_barrier; setprio MFMA x16; s_barrier}. vmcnt(4) counted at Ph4.
// Mapping: x=b&7 (XCD), bm=(q&((1<<BMBITS)-1))*8+x — all bn-blocks of one
// A-panel co-resident on one XCD (R8-validated, FETCH ~= ideal).
template <int NKT, int NSPLIT, int BMBITS, int MROWS>
__global__ __launch_bounds__(512) void gemm_dp(
    const unsigned short* __restrict__ Ab,
    const unsigned short* __restrict__ Bt,
    float* __restrict__ C, int Kp) {
  extern __shared__ unsigned short lds[];  // 8 * 8192 shorts = 128 KB
  const int tid = threadIdx.x;
  const int wid = tid >> 6;
  const int lane = tid & 63;
  const int b = blockIdx.x;
  const int x = b & 7, q = b >> 3;
  const int bm = (q & ((1 << BMBITS) - 1)) * 8 + x;
  const int bn = (q >> BMBITS) & 3;
  const int sp = q >> (BMBITS + 2);
  const int wm = (wid >> 2) << 7;  // 0 / 128
  const int wn = (wid & 3) << 6;   // 0 / 64 / 128 / 192

  const int qk = NKT / NSPLIT, rrk = NKT % NSPLIT;
  const int kt0 = sp * qk + (sp < rrk ? sp : rrk);
  const int T = qk + (sp < rrk ? 1 : 0);
  float* Cp = C + (size_t)sp * MROWS * NB;

  const int g0 = ((lane >> 4) ^ (lane & 7)) * 8;        // kk=0
  const int g1 = ((4 + (lane >> 4)) ^ (lane & 7)) * 8;  // kk=1
  const int alo = (lane & 15) * 64;
  const int bhalf = (wn >> 7) << 1;
  const int ahalf = (wid >> 2) << 1;
  const int bsub = ((wn & 64) << 6) + alo;

#define STAGEH(TT, ISA, H)                                                     \
  do {                                                                         \
    const int tt_ = (TT);                                                      \
    const int kc_ = kt0 + (tt_ < T - 1 ? tt_ : T - 1);                         \
    const int par_ = tt_ & 1;                                                  \
    const unsigned short* M_ = (ISA) ? Ab : Bt;                                \
    const int br_ = ((ISA) ? bm : bn) << 8;                                    \
    _Pragma("unroll")                                                          \
    for (int L_ = 0; L_ < 2; ++L_) {                                           \
      const int s_ = L_ * 512 + tid;                                           \
      const int row_ = s_ >> 3;                                                \
      const int gl_ = (s_ & 7) ^ (row_ & 7);                                   \
      const unsigned short* g_ = M_ + (size_t)(br_ + ((H) << 7) + row_) * Kp   \
                                    + (kc_ << 6) + gl_ * 8;                    \
      unsigned short* l_ = lds + (((ISA) ? 0 : 4) + ((H) << 1) + par_) * 8192  \
                               + (size_t)(L_ * 512 + wid * 64) * 8;            \
      __builtin_amdgcn_global_load_lds(                                        \
          (const __attribute__((address_space(1))) void*)g_,                   \
          (__attribute__((address_space(3))) void*)l_, 16, 0, 0);              \
    }                                                                          \
  } while (0)

#define MFMA16(BV0, BV1, NF0, NF1)                                             \
  do {                                                                         \
    __builtin_amdgcn_s_setprio(1);                                             \
    _Pragma("unroll")                                                          \
    for (int mf_ = 0; mf_ < 8; ++mf_) {                                        \
      asm volatile("v_mfma_f32_16x16x32_bf16 %0, %1, %2, %0"                   \
                   : "+v"(acc[mf_][NF0]) : "v"(af[mf_]), "v"(BV0));            \
      asm volatile("v_mfma_f32_16x16x32_bf16 %0, %1, %2, %0"                   \
                   : "+v"(acc[mf_][NF1]) : "v"(af[mf_]), "v"(BV1));            \
    }                                                                          \
    __builtin_amdgcn_s_setprio(0);                                             \
  } while (0)

#define PHASE_SYNC()                                                           \
  do {                                                                         \
    __builtin_amdgcn_s_barrier();                                              \
    asm volatile("s_waitcnt lgkmcnt(0)" ::: "memory");                         \
    __builtin_amdgcn_sched_barrier(0);                                         \
  } while (0)

  f32x4 acc[8][4];
#pragma unroll
  for (int i = 0; i < 8; ++i)
#pragma unroll
    for (int j = 0; j < 4; ++j) acc[i][j] = (f32x4)(0.0f);

  STAGEH(0, 1, 0); STAGEH(0, 1, 1);
  STAGEH(0, 0, 0); STAGEH(0, 0, 1);
  STAGEH(1, 1, 0); STAGEH(1, 1, 1);
  asm volatile("s_waitcnt vmcnt(4)" ::: "memory");
  __builtin_amdgcn_s_barrier();

  for (int t = 0; t < T; ++t) {
    const int par = t & 1;
    const unsigned short* Ab_ = lds + (ahalf + par) * 8192 + alo;
    const unsigned short* Bb_ = lds + (4 + bhalf + par) * 8192 + bsub;
    short8 af[8], b0, b1;
    // ---- Ph1 ----
    STAGEH(t + 1, 0, 0);
#pragma unroll
    for (int mf = 0; mf < 8; ++mf)
      af[mf] = *reinterpret_cast<const short8*>(Ab_ + mf * 1024 + g0);
    b0 = *reinterpret_cast<const short8*>(Bb_ + 0 * 1024 + g0);
    b1 = *reinterpret_cast<const short8*>(Bb_ + 1 * 1024 + g0);
    PHASE_SYNC();
    MFMA16(b0, b1, 0, 1);
    __builtin_amdgcn_s_barrier();
    // ---- Ph2 ----
    STAGEH(t + 1, 0, 1);
    b0 = *reinterpret_cast<const short8*>(Bb_ + 2 * 1024 + g0);
    b1 = *reinterpret_cast<const short8*>(Bb_ + 3 * 1024 + g0);
    PHASE_SYNC();
    MFMA16(b0, b1, 2, 3);
    __builtin_amdgcn_s_barrier();
    // ---- Ph3 ----
#pragma unroll
    for (int mf = 0; mf < 8; ++mf)
      af[mf] = *reinterpret_cast<const short8*>(Ab_ + mf * 1024 + g1);
    b0 = *reinterpret_cast<const short8*>(Bb_ + 2 * 1024 + g1);
    b1 = *reinterpret_cast<const short8*>(Bb_ + 3 * 1024 + g1);
    PHASE_SYNC();
    MFMA16(b0, b1, 2, 3);
    __builtin_amdgcn_s_barrier();
    // ---- Ph4 ----
    STAGEH(t + 2, 1, 0); STAGEH(t + 2, 1, 1);
    b0 = *reinterpret_cast<const short8*>(Bb_ + 0 * 1024 + g1);
    b1 = *reinterpret_cast<const short8*>(Bb_ + 1 * 1024 + g1);
    asm volatile("s_waitcnt vmcnt(4)" ::: "memory");
    PHASE_SYNC();
    MFMA16(b0, b1, 0, 1);
    __builtin_amdgcn_s_barrier();
  }
#undef STAGEH
#undef MFMA16
#undef PHASE_SYNC

  // epilogue: C/D layout col=lane&15, row=(lane>>4)*4+reg  [R7-R9 validated]
#pragma unroll
  for (int mf = 0; mf < 8; ++mf) {
    const int rb = (bm << 8) + wm + mf * 16 + ((lane >> 4) << 2);
#pragma unroll
    for (int nf = 0; nf < 4; ++nf) {
      const int col = (bn << 8) + wn + nf * 16 + (lane & 15);
#pragma unroll
      for (int r = 0; r < 4; ++r)
        Cp[(size_t)(rb + r) * NB + col] = acc[mf][nf][r];
    }
  }
}

// ---- LDS-tiled conv (R9-validated): block = (uo, v-half, 32-n), all 16 co ----
__global__ __launch_bounds__(256) void conv_lds_kernel(
    const float* __restrict__ za, const float* __restrict__ zb,
    const float* __restrict__ zh, const float* __restrict__ w,
    const float* __restrict__ bias, unsigned short* __restrict__ tT) {
  __shared__ float zl[24 * 18 * 32];
  __shared__ float wl[1152];
  __shared__ float bl[16];
  const int b = blockIdx.x;
  const int nt = b & 31, vh = (b >> 5) & 1, uo = b >> 6;
  const int n0 = nt * 32;
  const int tid = threadIdx.x;
#pragma unroll
  for (int it = 0; it < 5; ++it) {
    const int idx = it * 256 + tid;
    if (idx < 1152) wl[idx] = w[idx];
  }
  if (tid < 16) bl[tid] = bias[tid];
  const int nl4 = (tid & 7) * 4;
#pragma unroll
  for (int it = 0; it < 13; ++it) {
    const int R = it * 32 + (tid >> 3);
    if (R < 408) {
      const int ci = R / 51;
      const int rem = R - ci * 51;
      const int kh = rem / 17;
      const int vi = rem - kh * 17;
      const int u = 2 * uo + kh;
      const int v = vh * 16 + vi;
      float4 val = make_float4(0.f, 0.f, 0.f, 0.f);
      if (u < 32 && v < 32) {
        const size_t g = ((size_t)(ci * 1024 + u * 32 + v)) * 1024 + n0 + nl4;
        const float4 a4 = *reinterpret_cast<const float4*>(za + g);
        const float4 b4 = *reinterpret_cast<const float4*>(zb + g);
        val = make_float4(a4.x + b4.x, a4.y + b4.y, a4.z + b4.z, a4.w + b4.w);
      }
      *reinterpret_cast<float4*>(zl + ((ci * 3 + kh) * 18 + vi) * 32 + nl4) = val;
    }
  }
  __syncthreads();
  const int nl = tid & 31;
  const int cop = tid >> 5;
  const float hom = zh[n0 + nl];
  float acc[2][8];
#pragma unroll
  for (int c = 0; c < 2; ++c) {
    const float bb = bl[cop + c * 8] * hom;
#pragma unroll
    for (int vo = 0; vo < 8; ++vo) acc[c][vo] = bb;
  }
  for (int ci = 0; ci < 8; ++ci) {
#pragma unroll
    for (int kh = 0; kh < 3; ++kh) {
      const float* zr = zl + (ci * 3 + kh) * (18 * 32) + nl;
      float zv[17];
#pragma unroll
      for (int vi = 0; vi < 17; ++vi) zv[vi] = zr[vi * 32];
#pragma unroll
      for (int c = 0; c < 2; ++c) {
        const int co = cop + c * 8;
        const float* wp = wl + ((co * 8 + ci) * 3 + kh) * 3;
#pragma unroll
        for (int kw = 0; kw < 3; ++kw) {
          const float wv = wp[kw];
#pragma unroll
          for (int vo = 0; vo < 8; ++vo) acc[c][vo] += wv * zv[2 * vo + kw];
        }
      }
    }
  }
#pragma unroll
  for (int c = 0; c < 2; ++c) {
    const int co = cop + c * 8;
    unsigned short o[8];
#pragma unroll
    for (int vo = 0; vo < 8; ++vo) o[vo] = f2bf(acc[c][vo]);
    uint4 pv;
    pv.x = (unsigned)o[0] | ((unsigned)o[1] << 16);
    pv.y = (unsigned)o[2] | ((unsigned)o[3] << 16);
    pv.z = (unsigned)o[4] | ((unsigned)o[5] << 16);
    pv.w = (unsigned)o[6] | ((unsigned)o[7] << 16);
    *reinterpret_cast<uint4*>(
        tT + (size_t)(n0 + nl) * KP2 + co * 256 + uo * 16 + vh * 8) = pv;
  }
}

// ---- tT rows 4096..4159: hom row + zero pad ----
__global__ __launch_bounds__(256) void homrow_kernel(
    const float* __restrict__ zh, unsigned short* __restrict__ tT) {
  const int n = blockIdx.x * 256 + threadIdx.x;
  unsigned short* p = tT + (size_t)n * KP2 + 4096;
  uint4 z4 = make_uint4(0u, 0u, 0u, 0u);
  uint4 h4 = z4;
  h4.x = (unsigned)f2bf(zh[n]);
  *reinterpret_cast<uint4*>(p) = h4;
#pragma unroll
  for (int i = 1; i < 8; ++i) *reinterpret_cast<uint4*>(p + i * 8) = z4;
}

// ---- final sum of 4 split-K partials -> d_out rows 0..4095 ----
__global__ __launch_bounds__(256) void sum4_kernel(
    const float* __restrict__ p, float* __restrict__ out, int n4) {
  const int i = blockIdx.x * 256 + threadIdx.x;
  if (i >= n4) return;
  const size_t stride4 = (size_t)M2 * NB / 4;
  const float4* p4 = (const float4*)p;
  float4 a = p4[i];
  float4 b = p4[i + stride4];
  float4 c = p4[i + 2 * stride4];
  float4 d = p4[i + 3 * stride4];
  float4 r;
  r.x = (a.x + b.x) + (c.x + d.x);
  r.y = (a.y + b.y) + (c.y + d.y);
  r.z = (a.z + b.z) + (c.z + d.z);
  r.w = (a.w + b.w) + (c.w + d.w);
  reinterpret_cast<float4*>(out)[i] = r;
}

// ---- out row 4096: wave-per-column dot over bf16 A2 row x tT ----
__global__ __launch_bounds__(256) void outrow_kernel(
    const unsigned short* __restrict__ A2row,
    const unsigned short* __restrict__ tT, float* __restrict__ out) {
  const int wid = threadIdx.x >> 6, lane = threadIdx.x & 63;
  const int n = blockIdx.x * 4 + wid;
  const unsigned short* trow = tT + (size_t)n * KP2;
  float acc = 0.f;
#pragma unroll
  for (int it = 0; it < 9; ++it) {
    const int i8 = it * 64 + lane;
    if (i8 < KP2 / 8) {
      short8 tv = *reinterpret_cast<const short8*>(trow + i8 * 8);
      short8 av = *reinterpret_cast<const short8*>(A2row + i8 * 8);
#pragma unroll
      for (int j = 0; j < 8; ++j)
        acc += bf2f((unsigned short)tv[j]) * bf2f((unsigned short)av[j]);
    }
  }
#pragma unroll
  for (int m = 1; m <= 32; m <<= 1) acc += __shfl_xor(acc, m);
  if (lane == 0) out[(size_t)4096 * NB + n] = acc;
}

extern "C" void kernel_launch(void* const* d_in, const int* in_sizes, int n_in,
                              void* d_out, int out_size, void* d_ws, size_t ws_size,
                              hipStream_t stream) {
  const float* w    = (const float*)d_in[0];  // (16,8,3,3)
  const float* bias = (const float*)d_in[1];  // (16,)
  const float* A    = (const float*)d_in[2];  // (4097,4097)
  const float* Ainv = (const float*)d_in[3];  // (8193,8193)
  const float* x    = (const float*)d_in[4];  // (8193,1024)
  float* out = (float*)d_out;                 // (4097,1024)

  // Workspace (227.8 MB <= proven 231.5): R13 plan
  char* ws = (char*)d_ws;
  const size_t o_xT = (size_t)M1 * KP1 * 2;
  const size_t o_z2 = o_xT + (size_t)NB * KP1 * 2;
  const size_t o_tT = o_z2 + (size_t)2 * M1 * NB * 4;
  const size_t o_zh = o_tT + (size_t)NB * KP2 * 2;
  unsigned short* Ainv_b = (unsigned short*)ws;
  unsigned short* xT_b   = (unsigned short*)(ws + o_xT);
  float*          z2     = (float*)(ws + o_z2);
  unsigned short* tT_b   = (unsigned short*)(ws + o_tT);
  float*          zh     = (float*)(ws + o_zh);
  unsigned short* A2_b   = (unsigned short*)ws;
  float*          outp   = (float*)(ws + (size_t)OUT_DIM * KP2 * 2);
  (void)ws_size; (void)in_sizes; (void)n_in; (void)out_size;

  hipFuncSetAttribute((const void*)gemm_dp<129, 2, 2, M1>,
                      hipFuncAttributeMaxDynamicSharedMemorySize, 131072);
  hipFuncSetAttribute((const void*)gemm_dp<65, 4, 1, M2>,
                      hipFuncAttributeMaxDynamicSharedMemorySize, 131072);

  // 1) zero zh (hom accumulator)
  zero_kernel<<<1, 256, 0, stream>>>((float4*)zh, 256);
  // 2) Ainv rows 0..8191 -> padded bf16
  cvt_pad_kernel<<<(M1 * KP1 / 4) / 256, 256, 0, stream>>>(
      Ainv, Ainv_b, IN_DIM, IN_DIM, M1, KP1);
  // 3) x -> x^T bf16 + fused zh = Ainv[8192,:] @ x
  transpose_cvt_zh_kernel<<<(KP1 / 32) * (NB / 32), 256, 0, stream>>>(
      x, xT_b, Ainv + (size_t)8192 * IN_DIM, zh, IN_DIM, NB, KP1);
  // 4) z{a,b} = Ainv @ x  (8-barrier 4-phase GEMM, exactly 256 blocks)
  gemm_dp<129, 2, 2, M1><<<256, 512, 131072, stream>>>(
      Ainv_b, xT_b, z2, KP1);
  // 5) t^T rows 0..4095 = conv(za+zb, hom=zh)  (LDS-tiled, 1024 blocks)
  conv_lds_kernel<<<1024, 256, 0, stream>>>(
      z2, z2 + (size_t)M1 * NB, zh, w, bias, tT_b);
  // 5b) t^T rows 4096..4159 = hom + zero pad
  homrow_kernel<<<4, 256, 0, stream>>>(zh, tT_b);
  // 6) A rows 0..4096 -> padded bf16 (aliases dead Ainv_b)
  cvt_pad_kernel<<<(OUT_DIM * KP2 / 4 + 255) / 256, 256, 0, stream>>>(
      A, A2_b, OUT_DIM, OUT_DIM, OUT_DIM, KP2);
  // 7) outp[0..3] = A @ t  (8-barrier 4-phase GEMM, exactly 256 blocks)
  gemm_dp<65, 4, 1, M2><<<256, 512, 131072, stream>>>(
      A2_b, tT_b, outp, KP2);
  // 8) out rows 0..4095 = sum of partials
  sum4_kernel<<<(M2 * NB / 4) / 256, 256, 0, stream>>>(
      outp, out, M2 * NB / 4);
  // 9) out row 4096 = A2[4096,:] @ t
  outrow_kernel<<<NB / 4, 256, 0, stream>>>(
      A2_b + (size_t)4096 * KP2, tT_b, out);
}